// Round 3
// baseline (950.894 us; speedup 1.0000x reference)
//
#include <hip/hip_runtime.h>

#define DIM 384
#define HEADS 12
#define HD 32
#define NTOK 49
#define NWIN 4096
#define MTOT (NWIN*NTOK)   // 200704 = 1568 * 128
#define PSTR 72            // padded LDS row stride (elements) for P and V^T

typedef __attribute__((ext_vector_type(8))) __bf16 bf16x8;
typedef __attribute__((ext_vector_type(4))) float f32x4;

static __device__ __forceinline__ f32x4 mfma16(bf16x8 a, bf16x8 b, f32x4 c) {
  return __builtin_amdgcn_mfma_f32_16x16x32_bf16(a, b, c, 0, 0, 0);
}

// async global->LDS, 16B per lane: dest = lds_base(wave-uniform) + lane*16
static __device__ __forceinline__ void gload_lds16(const void* g, void* l) {
  __builtin_amdgcn_global_load_lds(
      (const __attribute__((address_space(1))) unsigned int*)g,
      (__attribute__((address_space(3))) unsigned int*)l, 16, 0, 0);
}

// ---------------- prep: weights -> bf16, bias table expand ----------------
__global__ void k_prep(const float* __restrict__ qw, const float* __restrict__ kvw,
                       const float* __restrict__ pw, const float* __restrict__ rel_table,
                       const int* __restrict__ rel_index,
                       __bf16* __restrict__ qw_bf, __bf16* __restrict__ kvw_bf,
                       __bf16* __restrict__ pw_bf, float* __restrict__ bias_pad) {
  int i = blockIdx.x * 256 + threadIdx.x;
  if (i < DIM*DIM)   qw_bf[i] = (__bf16)qw[i];
  if (i < 2*DIM*DIM) kvw_bf[i] = (__bf16)kvw[i];
  if (i < DIM*DIM)   pw_bf[i] = (__bf16)pw[i];
  if (i < HEADS*64*64) {
    int h = i >> 12, rem = i & 4095, q = rem >> 6, k = rem & 63;
    float v;
    if (k >= NTOK)      v = -1e30f;   // key padding: masks softmax for free
    else if (q >= NTOK) v = 0.0f;     // query padding rows are discarded
    else v = rel_table[rel_index[q*NTOK + k] * HEADS + h];
    bias_pad[i] = v;
  }
}

// ---------------- streaming f32 -> bf16 convert (x,y), 8 elems/thread/iter ----
__global__ __launch_bounds__(256) void k_cvt(const float* __restrict__ x,
                                             const float* __restrict__ y,
                                             __bf16* __restrict__ xb,
                                             __bf16* __restrict__ yb) {
  const size_t NCH = (size_t)MTOT * DIM / 8;   // chunks per tensor
  size_t i = (size_t)blockIdx.x * 256 + threadIdx.x;
  size_t stride = (size_t)gridDim.x * 256;
  for (; i < 2*NCH; i += stride) {
    const float* s; __bf16* d; size_t c;
    if (i < NCH) { s = x; d = xb; c = i; } else { s = y; d = yb; c = i - NCH; }
    float4 v0 = *(const float4*)(s + c*8);
    float4 v1 = *(const float4*)(s + c*8 + 4);
    bf16x8 t;
    t[0]=(__bf16)v0.x; t[1]=(__bf16)v0.y; t[2]=(__bf16)v0.z; t[3]=(__bf16)v0.w;
    t[4]=(__bf16)v1.x; t[5]=(__bf16)v1.y; t[6]=(__bf16)v1.z; t[7]=(__bf16)v1.w;
    *(bf16x8*)(d + c*8) = t;
  }
}

// ---------------- fused QKV GEMM, all-bf16 LDS (row-paired XOR swizzle) ------
// LDS tile = 128 logical rows x 32 bf16 (64B) stored as 64 phys rows x 128B:
//   phys row P holds logical rows {2P, 2P+1}; 16B slot s of half h holds
//   cols 8*(s ^ (P&3)). Staged via pre-swizzled global source (rule #21).
__global__ __launch_bounds__(256, 4) void k_qkv(
    const __bf16* __restrict__ xb, const __bf16* __restrict__ yb,
    const __bf16* __restrict__ qw_bf, const __bf16* __restrict__ kvw_bf,
    const float* __restrict__ q_b, const float* __restrict__ kv_b,
    __bf16* __restrict__ Qws, __bf16* __restrict__ Kws, __bf16* __restrict__ Vws)
{
  // 14112 = 8 * 1764 : bijective XCD swizzle; 9 col-tiles of one mtile stay on one XCD
  int b = blockIdx.x;
  int orig = (b & 7) * 1764 + (b >> 3);
  int mtile = orig / 9;
  int nt9 = orig - mtile*9;
  const __bf16* A; const __bf16* Bw; const float* bias; __bf16* Cout;
  int wrow0, col0;
  if (nt9 < 3) { A = xb; Bw = qw_bf; bias = q_b; Cout = Qws; wrow0 = nt9*128; col0 = wrow0; }
  else {
    A = yb; Bw = kvw_bf; bias = kv_b; wrow0 = (nt9-3)*128;
    if (wrow0 < DIM) { Cout = Kws; col0 = wrow0; } else { Cout = Vws; col0 = wrow0 - DIM; }
  }
  bias += wrow0;

  __shared__ __align__(16) __bf16 As[2][128*32];   // 8 KB each
  __shared__ __align__(16) __bf16 Bs[2][128*32];   // 8 KB each

  int t = threadIdx.x, lane = t & 63, wave = t >> 6;
  int l15 = lane & 15, g = lane >> 4;
  int wr = (wave >> 1) * 64, wc = (wave & 1) * 64;
  int row0b = mtile*128;

  // staging source: lane n of instr j fetches logical row (wave*2+j)*16 + sr,
  // col-block scb (paired-row + 2-bit XOR pre-swizzle)
  int sr  = 2*(lane >> 3) + ((lane >> 2) & 1);
  int scb = (lane & 3) ^ ((lane >> 3) & 3);
  const __bf16* asrc[2]; const __bf16* bsrc[2];
  #pragma unroll
  for (int j = 0; j < 2; ++j) {
    int ar = (wave*2 + j)*16 + sr;
    asrc[j] = A  + (size_t)(row0b + ar)*DIM + scb*8;
    bsrc[j] = Bw + (size_t)(wrow0 + ar)*DIM + scb*8;
  }

  f32x4 acc[4][4];
  #pragma unroll
  for (int a=0;a<4;a++)
    #pragma unroll
    for (int bb=0;bb<4;bb++) acc[a][bb] = (f32x4){0.f,0.f,0.f,0.f};

  // prologue: stage K-step 0
  #pragma unroll
  for (int j = 0; j < 2; ++j) {
    gload_lds16(asrc[j], (char*)&As[0][0] + (wave*2+j)*1024);
    gload_lds16(bsrc[j], (char*)&Bs[0][0] + (wave*2+j)*1024);
  }
  __syncthreads();

  // ds_read address: logical row r at byte r*64 + 16*(g ^ ((r>>1)&3)); with
  // r = base16 + l15 and base16 % 16 == 0, (r>>1)&3 == (l15>>1)&3 — lane-const.
  int lslot = l15*64 + ((g ^ ((l15 >> 1) & 3)) << 4);

  int buf = 0;
  #pragma unroll 2
  for (int kt = 0; kt < 12; ++kt) {
    if (kt < 11) {
      int kk = (kt+1)*32;
      #pragma unroll
      for (int j = 0; j < 2; ++j) {
        gload_lds16(asrc[j] + kk, (char*)&As[buf^1][0] + (wave*2+j)*1024);
        gload_lds16(bsrc[j] + kk, (char*)&Bs[buf^1][0] + (wave*2+j)*1024);
      }
    }
    bf16x8 af[4], bfv[4];
    #pragma unroll
    for (int a=0;a<4;a++)
      af[a]  = *(const bf16x8*)((const char*)&As[buf][0] + (wr + a*16)*64 + lslot);
    #pragma unroll
    for (int bb=0;bb<4;bb++)
      bfv[bb] = *(const bf16x8*)((const char*)&Bs[buf][0] + (wc + bb*16)*64 + lslot);
    #pragma unroll
    for (int a=0;a<4;a++)
      #pragma unroll
      for (int bb=0;bb<4;bb++)
        acc[a][bb] = mfma16(af[a], bfv[bb], acc[a][bb]);
    __syncthreads();
    buf ^= 1;
  }

  #pragma unroll
  for (int a=0;a<4;a++) {
    #pragma unroll
    for (int bb=0;bb<4;bb++) {
      int colw = wc + bb*16 + l15;
      float bi = bias[colw];
      size_t cbase = (size_t)(row0b + wr + a*16 + 4*g)*DIM + (col0 + colw);
      #pragma unroll
      for (int r=0;r<4;r++)
        Cout[cbase + (size_t)r*DIM] = (__bf16)(acc[a][bb][r] + bi);
    }
  }
}

// ---------------- per-window attention (12 heads), writes attn_out over Q ----------------
__global__ __launch_bounds__(256) void k_attn(
    __bf16* qao,   // Q in, attn_out out (ALIASED — intentionally not restrict)
    const __bf16* __restrict__ Kws, const __bf16* __restrict__ Vws,
    const float* __restrict__ bias_pad)
{
  __shared__ __align__(16) __bf16 Psh[4][64*PSTR];
  __shared__ __align__(16) __bf16 VTsh[4][32*PSTR];
  int b = blockIdx.x;
  int lane = threadIdx.x & 63, wave = threadIdx.x >> 6;
  int l15 = lane & 15, g = lane >> 4;
  __bf16* Pw  = Psh[wave];
  __bf16* VTw = VTsh[wave];
  size_t rowbase = (size_t)b * NTOK * DIM;
  const float scale = 0.17677669529663687f;  // 32^-0.5

  for (int e = lane; e < 32*15; e += 64) {
    int d = e / 15, k = 49 + (e - d*15);
    VTw[d*PSTR + k] = (__bf16)0.0f;
  }

  for (int hh = 0; hh < 3; hh++) {
    int h = wave + hh*4;
    for (int e = lane; e < NTOK*HD; e += 64) {
      int k = e >> 5, d = e & 31;
      VTw[d*PSTR + k] = Vws[rowbase + (size_t)k*DIM + h*HD + d];
    }
    bf16x8 qf[4], kf[4];
    #pragma unroll
    for (int mt=0; mt<4; mt++) {
      int q = 16*mt + l15; if (q > 48) q = 48;
      qf[mt] = *(const bf16x8*)(qao + rowbase + (size_t)q*DIM + h*HD + g*8);
    }
    #pragma unroll
    for (int nt=0; nt<4; nt++) {
      int kk = 16*nt + l15; if (kk > 48) kk = 48;
      kf[nt] = *(const bf16x8*)(Kws + rowbase + (size_t)kk*DIM + h*HD + g*8);
    }
    f32x4 sacc[4][4];
    #pragma unroll
    for (int mt=0; mt<4; mt++)
      #pragma unroll
      for (int nt=0; nt<4; nt++)
        sacc[mt][nt] = mfma16(qf[mt], kf[nt], (f32x4){0.f,0.f,0.f,0.f});

    const float* bt = bias_pad + h*4096;
    float rs[4][4];
    #pragma unroll
    for (int mt=0; mt<4; mt++) {
      #pragma unroll
      for (int r=0; r<4; r++) {
        int q = 16*mt + 4*g + r;
        float v0 = sacc[mt][0][r]*scale + bt[q*64 +  0 + l15];
        float v1 = sacc[mt][1][r]*scale + bt[q*64 + 16 + l15];
        float v2 = sacc[mt][2][r]*scale + bt[q*64 + 32 + l15];
        float v3 = sacc[mt][3][r]*scale + bt[q*64 + 48 + l15];
        float m = fmaxf(fmaxf(v0,v1), fmaxf(v2,v3));
        #pragma unroll
        for (int off=1; off<16; off<<=1) m = fmaxf(m, __shfl_xor(m, off));
        v0 = __expf(v0-m); v1 = __expf(v1-m); v2 = __expf(v2-m); v3 = __expf(v3-m);
        float s = v0+v1+v2+v3;
        #pragma unroll
        for (int off=1; off<16; off<<=1) s += __shfl_xor(s, off);
        rs[mt][r] = s;
        Pw[q*PSTR +  0 + l15] = (__bf16)v0;
        Pw[q*PSTR + 16 + l15] = (__bf16)v1;
        Pw[q*PSTR + 32 + l15] = (__bf16)v2;
        Pw[q*PSTR + 48 + l15] = (__bf16)v3;
      }
    }

    #pragma unroll
    for (int mt=0; mt<4; mt++) {
      #pragma unroll
      for (int dt=0; dt<2; dt++) {
        f32x4 o = (f32x4){0.f,0.f,0.f,0.f};
        #pragma unroll
        for (int ks=0; ks<2; ks++) {
          bf16x8 pa = *(const bf16x8*)(Pw  + (16*mt + l15)*PSTR + 32*ks + 8*g);
          bf16x8 vb = *(const bf16x8*)(VTw + (16*dt + l15)*PSTR + 32*ks + 8*g);
          o = mfma16(pa, vb, o);
        }
        #pragma unroll
        for (int r=0; r<4; r++) {
          int q = 16*mt + 4*g + r;
          if (q < NTOK)
            qao[rowbase + (size_t)q*DIM + h*HD + 16*dt + l15] = (__bf16)(o[r] / rs[mt][r]);
        }
      }
    }
  }
}

// ---------------- output projection, all-bf16 LDS: out = AO @ proj_w^T + b ----
__global__ __launch_bounds__(256, 4) void k_proj(
    const __bf16* __restrict__ Aao, const __bf16* __restrict__ pw_bf,
    const float* __restrict__ pb, float* __restrict__ out)
{
  // 4704 = 8 * 588 : bijective XCD swizzle
  int b = blockIdx.x;
  int orig = (b & 7) * 588 + (b >> 3);
  int mtile = orig / 3;
  int nt = orig - mtile*3;
  int lane = threadIdx.x & 63, wave = threadIdx.x >> 6;
  int l15 = lane & 15, g = lane >> 4;
  int wr = (wave >> 1) * 64, wc = (wave & 1) * 64;
  int row0b = mtile*128;
  int col00 = nt*128;

  __shared__ __align__(16) __bf16 As[2][128*32];
  __shared__ __align__(16) __bf16 Bs[2][128*32];

  int sr  = 2*(lane >> 3) + ((lane >> 2) & 1);
  int scb = (lane & 3) ^ ((lane >> 3) & 3);
  const __bf16* asrc[2]; const __bf16* bsrc[2];
  #pragma unroll
  for (int j = 0; j < 2; ++j) {
    int ar = (wave*2 + j)*16 + sr;
    asrc[j] = Aao   + (size_t)(row0b + ar)*DIM + scb*8;
    bsrc[j] = pw_bf + (size_t)(col00 + ar)*DIM + scb*8;
  }

  f32x4 acc[4][4];
  #pragma unroll
  for (int a=0;a<4;a++)
    #pragma unroll
    for (int bb=0;bb<4;bb++) acc[a][bb] = (f32x4){0.f,0.f,0.f,0.f};

  #pragma unroll
  for (int j = 0; j < 2; ++j) {
    gload_lds16(asrc[j], (char*)&As[0][0] + (wave*2+j)*1024);
    gload_lds16(bsrc[j], (char*)&Bs[0][0] + (wave*2+j)*1024);
  }
  __syncthreads();

  int lslot = l15*64 + ((g ^ ((l15 >> 1) & 3)) << 4);

  int buf = 0;
  #pragma unroll 2
  for (int kt = 0; kt < 12; ++kt) {
    if (kt < 11) {
      int kk = (kt+1)*32;
      #pragma unroll
      for (int j = 0; j < 2; ++j) {
        gload_lds16(asrc[j] + kk, (char*)&As[buf^1][0] + (wave*2+j)*1024);
        gload_lds16(bsrc[j] + kk, (char*)&Bs[buf^1][0] + (wave*2+j)*1024);
      }
    }
    bf16x8 af[4], bfv[4];
    #pragma unroll
    for (int a=0;a<4;a++)
      af[a]  = *(const bf16x8*)((const char*)&As[buf][0] + (wr + a*16)*64 + lslot);
    #pragma unroll
    for (int bb=0;bb<4;bb++)
      bfv[bb] = *(const bf16x8*)((const char*)&Bs[buf][0] + (wc + bb*16)*64 + lslot);
    #pragma unroll
    for (int a=0;a<4;a++)
      #pragma unroll
      for (int bb=0;bb<4;bb++)
        acc[a][bb] = mfma16(af[a], bfv[bb], acc[a][bb]);
    __syncthreads();
    buf ^= 1;
  }

  #pragma unroll
  for (int a=0;a<4;a++) {
    #pragma unroll
    for (int bb=0;bb<4;bb++) {
      int col = col00 + wc + bb*16 + l15;
      float bi = pb[col];
      size_t cbase = (size_t)(row0b + wr + a*16 + 4*g)*DIM + col;
      #pragma unroll
      for (int r=0;r<4;r++)
        out[cbase + (size_t)r*DIM] = acc[a][bb][r] + bi;
    }
  }
}

extern "C" void kernel_launch(void* const* d_in, const int* in_sizes, int n_in,
                              void* d_out, int out_size, void* d_ws, size_t ws_size,
                              hipStream_t stream)
{
  const float* x   = (const float*)d_in[0];
  const float* y   = (const float*)d_in[1];
  const float* qw  = (const float*)d_in[2];
  const float* qb  = (const float*)d_in[3];
  const float* kvw = (const float*)d_in[4];
  const float* kvb = (const float*)d_in[5];
  const float* pw  = (const float*)d_in[6];
  const float* pb  = (const float*)d_in[7];
  const float* rt  = (const float*)d_in[8];
  const int*   ri  = (const int*)d_in[9];
  float* out = (float*)d_out;

  char* ws = (char*)d_ws;
  const size_t WS_NEEDED = 1376256ull + 3ull*154140672ull;
  if (ws_size < WS_NEEDED) return;

  __bf16* qw_bf    = (__bf16*)(ws);
  __bf16* kvw_bf   = (__bf16*)(ws + 294912);
  __bf16* pw_bf    = (__bf16*)(ws + 884736);
  float*  bias_pad = (float*)(ws + 1179648);
  __bf16* Qws      = (__bf16*)(ws + 1376256);
  __bf16* Kws      = Qws + (size_t)MTOT*DIM;
  __bf16* Vws      = Kws + (size_t)MTOT*DIM;

  // d_out (308,281,344 B) is dead until k_proj fully rewrites it — use it as
  // scratch for the bf16 copies of x and y (exactly 2 * 154,140,672 B).
  __bf16* xb = (__bf16*)d_out;
  __bf16* yb = xb + (size_t)MTOT*DIM;

  k_prep<<<dim3(1152), dim3(256), 0, stream>>>(qw, kvw, pw, rt, ri, qw_bf, kvw_bf, pw_bf, bias_pad);
  k_cvt <<<dim3(4096), dim3(256), 0, stream>>>(x, y, xb, yb);
  k_qkv <<<dim3(1568*9), dim3(256), 0, stream>>>(xb, yb, qw_bf, kvw_bf, qb, kvb, Qws, Kws, Vws);
  k_attn<<<dim3(NWIN), dim3(256), 0, stream>>>(Qws, Kws, Vws, bias_pad);
  k_proj<<<dim3(1568*3), dim3(256), 0, stream>>>(Qws, pw_bf, pb, out);
}

// Round 4
// 863.656 us; speedup vs baseline: 1.1010x; 1.1010x over previous
//
#include <hip/hip_runtime.h>

#define DIM 384
#define HEADS 12
#define HD 32
#define NTOK 49
#define NWIN 4096
#define MTOT (NWIN*NTOK)   // 200704 = 1568 * 128
#define PSTR 72            // padded LDS row stride (elements) for P and V^T

typedef __attribute__((ext_vector_type(8))) __bf16 bf16x8;
typedef __attribute__((ext_vector_type(4))) float f32x4;

static __device__ __forceinline__ f32x4 mfma16(bf16x8 a, bf16x8 b, f32x4 c) {
  return __builtin_amdgcn_mfma_f32_16x16x32_bf16(a, b, c, 0, 0, 0);
}

// async global->LDS, 16B per lane: dest = lds_base(wave-uniform) + lane*16
static __device__ __forceinline__ void gload_lds16(const void* g, void* l) {
  __builtin_amdgcn_global_load_lds(
      (const __attribute__((address_space(1))) unsigned int*)g,
      (__attribute__((address_space(3))) unsigned int*)l, 16, 0, 0);
}

static __device__ __forceinline__ bf16x8 cvt8(float4 v0, float4 v1) {
  bf16x8 t;
  t[0]=(__bf16)v0.x; t[1]=(__bf16)v0.y; t[2]=(__bf16)v0.z; t[3]=(__bf16)v0.w;
  t[4]=(__bf16)v1.x; t[5]=(__bf16)v1.y; t[6]=(__bf16)v1.z; t[7]=(__bf16)v1.w;
  return t;
}

// ---------------- prep: weights -> bf16, bias table expand ----------------
__global__ void k_prep(const float* __restrict__ qw, const float* __restrict__ kvw,
                       const float* __restrict__ pw, const float* __restrict__ rel_table,
                       const int* __restrict__ rel_index,
                       __bf16* __restrict__ qw_bf, __bf16* __restrict__ kvw_bf,
                       __bf16* __restrict__ pw_bf, float* __restrict__ bias_pad) {
  int i = blockIdx.x * 256 + threadIdx.x;
  if (i < DIM*DIM)   qw_bf[i] = (__bf16)qw[i];
  if (i < 2*DIM*DIM) kvw_bf[i] = (__bf16)kvw[i];
  if (i < DIM*DIM)   pw_bf[i] = (__bf16)pw[i];
  if (i < HEADS*64*64) {
    int h = i >> 12, rem = i & 4095, q = rem >> 6, k = rem & 63;
    float v;
    if (k >= NTOK)      v = -1e30f;   // key padding: masks softmax for free
    else if (q >= NTOK) v = 0.0f;     // query padding rows are discarded
    else v = rel_table[rel_index[q*NTOK + k] * HEADS + h];
    bias_pad[i] = v;
  }
}

// ---------------- fused QKV GEMM: f32 A reg-staged -> bf16 LDS (swizzled) ----
// A staging (T14 split): thread t owns logical row t>>1, cols [16*(t&1),+16).
// Loads 4x float4 early, converts (cvt_pk) and ds_writes late; bank-verified
// conflict-free under the same paired-row 2-bit XOR swizzle the reads use.
__global__ __launch_bounds__(256, 4) void k_qkv(
    const float* __restrict__ x, const float* __restrict__ y,
    const __bf16* __restrict__ qw_bf, const __bf16* __restrict__ kvw_bf,
    const float* __restrict__ q_b, const float* __restrict__ kv_b,
    __bf16* __restrict__ Qws, __bf16* __restrict__ Kws, __bf16* __restrict__ Vws)
{
  // 14112 = 8 * 1764 : bijective XCD swizzle; 9 col-tiles of one mtile stay on one XCD
  int b = blockIdx.x;
  int orig = (b & 7) * 1764 + (b >> 3);
  int mtile = orig / 9;
  int nt9 = orig - mtile*9;
  const float* A; const __bf16* Bw; const float* bias; __bf16* Cout;
  int wrow0, col0;
  if (nt9 < 3) { A = x; Bw = qw_bf; bias = q_b; Cout = Qws; wrow0 = nt9*128; col0 = wrow0; }
  else {
    A = y; Bw = kvw_bf; bias = kv_b; wrow0 = (nt9-3)*128;
    if (wrow0 < DIM) { Cout = Kws; col0 = wrow0; } else { Cout = Vws; col0 = wrow0 - DIM; }
  }
  bias += wrow0;

  __shared__ __align__(16) __bf16 As[2][128*32];   // 8 KB each
  __shared__ __align__(16) __bf16 Bs[2][128*32];   // 8 KB each

  int t = threadIdx.x, lane = t & 63, wave = t >> 6;
  int l15 = lane & 15, g = lane >> 4;
  int wr = (wave >> 1) * 64, wc = (wave & 1) * 64;
  int row0b = mtile*128;

  // ---- A staging geometry (reg path) ----
  int srow = t >> 1, sh = t & 1;
  const float* asrc = A + (size_t)(row0b + srow)*DIM + sh*16;
  int swk = (srow >> 1) & 3;
  unsigned lds_a0 = srow*64 + ((( (2*sh)   ) ^ swk) << 4);
  unsigned lds_a1 = srow*64 + ((( (2*sh)|1 ) ^ swk) << 4);

  // ---- B staging geometry (global_load_lds, pre-swizzled source) ----
  int sr  = 2*(lane >> 3) + ((lane >> 2) & 1);
  int scb = (lane & 3) ^ ((lane >> 3) & 3);
  const __bf16* bsrc[2];
  #pragma unroll
  for (int j = 0; j < 2; ++j)
    bsrc[j] = Bw + (size_t)(wrow0 + (wave*2 + j)*16 + sr)*DIM + scb*8;

  f32x4 acc[4][4];
  #pragma unroll
  for (int a=0;a<4;a++)
    #pragma unroll
    for (int bb=0;bb<4;bb++) acc[a][bb] = (f32x4){0.f,0.f,0.f,0.f};

  float4 r0, r1, r2, r3;
  // prologue: stage K-step 0
  r0 = *(const float4*)(asrc);     r1 = *(const float4*)(asrc + 4);
  r2 = *(const float4*)(asrc + 8); r3 = *(const float4*)(asrc + 12);
  #pragma unroll
  for (int j = 0; j < 2; ++j)
    gload_lds16(bsrc[j], (char*)&Bs[0][0] + (wave*2+j)*1024);
  *(bf16x8*)((char*)&As[0][0] + lds_a0) = cvt8(r0, r1);
  *(bf16x8*)((char*)&As[0][0] + lds_a1) = cvt8(r2, r3);
  __syncthreads();

  // ds_read address: logical row r at byte r*64 + 16*(g ^ ((r>>1)&3)); with
  // r = base16 + l15 and base16 % 16 == 0, (r>>1)&3 == (l15>>1)&3 — lane-const.
  int lslot = l15*64 + ((g ^ ((l15 >> 1) & 3)) << 4);

  int buf = 0;
  #pragma unroll 2
  for (int kt = 0; kt < 12; ++kt) {
    if (kt < 11) {
      int kk = (kt+1)*32;
      // issue next-tile loads EARLY (latency hides under this tile's MFMA)
      r0 = *(const float4*)(asrc + kk);     r1 = *(const float4*)(asrc + kk + 4);
      r2 = *(const float4*)(asrc + kk + 8); r3 = *(const float4*)(asrc + kk + 12);
      #pragma unroll
      for (int j = 0; j < 2; ++j)
        gload_lds16(bsrc[j] + kk, (char*)&Bs[buf^1][0] + (wave*2+j)*1024);
    }
    bf16x8 af[4], bfv[4];
    #pragma unroll
    for (int a=0;a<4;a++)
      af[a]  = *(const bf16x8*)((const char*)&As[buf][0] + (wr + a*16)*64 + lslot);
    #pragma unroll
    for (int bb=0;bb<4;bb++)
      bfv[bb] = *(const bf16x8*)((const char*)&Bs[buf][0] + (wc + bb*16)*64 + lslot);
    #pragma unroll
    for (int a=0;a<4;a++)
      #pragma unroll
      for (int bb=0;bb<4;bb++)
        acc[a][bb] = mfma16(af[a], bfv[bb], acc[a][bb]);
    if (kt < 11) {
      // write-late: convert and commit next tile after MFMAs issued
      *(bf16x8*)((char*)&As[buf^1][0] + lds_a0) = cvt8(r0, r1);
      *(bf16x8*)((char*)&As[buf^1][0] + lds_a1) = cvt8(r2, r3);
    }
    __syncthreads();
    buf ^= 1;
  }

  #pragma unroll
  for (int a=0;a<4;a++) {
    #pragma unroll
    for (int bb=0;bb<4;bb++) {
      int colw = wc + bb*16 + l15;
      float bi = bias[colw];
      size_t cbase = (size_t)(row0b + wr + a*16 + 4*g)*DIM + (col0 + colw);
      #pragma unroll
      for (int r=0;r<4;r++)
        Cout[cbase + (size_t)r*DIM] = (__bf16)(acc[a][bb][r] + bi);
    }
  }
}

// ---------------- per-window attention (12 heads), writes attn_out over Q ----------------
__global__ __launch_bounds__(256) void k_attn(
    __bf16* qao,   // Q in, attn_out out (ALIASED — intentionally not restrict)
    const __bf16* __restrict__ Kws, const __bf16* __restrict__ Vws,
    const float* __restrict__ bias_pad)
{
  __shared__ __align__(16) __bf16 Psh[4][64*PSTR];
  __shared__ __align__(16) __bf16 VTsh[4][32*PSTR];
  int b = blockIdx.x;
  int lane = threadIdx.x & 63, wave = threadIdx.x >> 6;
  int l15 = lane & 15, g = lane >> 4;
  __bf16* Pw  = Psh[wave];
  __bf16* VTw = VTsh[wave];
  size_t rowbase = (size_t)b * NTOK * DIM;
  const float scale = 0.17677669529663687f;  // 32^-0.5

  for (int e = lane; e < 32*15; e += 64) {
    int d = e / 15, k = 49 + (e - d*15);
    VTw[d*PSTR + k] = (__bf16)0.0f;
  }

  for (int hh = 0; hh < 3; hh++) {
    int h = wave + hh*4;
    for (int e = lane; e < NTOK*HD; e += 64) {
      int k = e >> 5, d = e & 31;
      VTw[d*PSTR + k] = Vws[rowbase + (size_t)k*DIM + h*HD + d];
    }
    bf16x8 qf[4], kf[4];
    #pragma unroll
    for (int mt=0; mt<4; mt++) {
      int q = 16*mt + l15; if (q > 48) q = 48;
      qf[mt] = *(const bf16x8*)(qao + rowbase + (size_t)q*DIM + h*HD + g*8);
    }
    #pragma unroll
    for (int nt=0; nt<4; nt++) {
      int kk = 16*nt + l15; if (kk > 48) kk = 48;
      kf[nt] = *(const bf16x8*)(Kws + rowbase + (size_t)kk*DIM + h*HD + g*8);
    }
    f32x4 sacc[4][4];
    #pragma unroll
    for (int mt=0; mt<4; mt++)
      #pragma unroll
      for (int nt=0; nt<4; nt++)
        sacc[mt][nt] = mfma16(qf[mt], kf[nt], (f32x4){0.f,0.f,0.f,0.f});

    const float* bt = bias_pad + h*4096;
    float rs[4][4];
    #pragma unroll
    for (int mt=0; mt<4; mt++) {
      #pragma unroll
      for (int r=0; r<4; r++) {
        int q = 16*mt + 4*g + r;
        float v0 = sacc[mt][0][r]*scale + bt[q*64 +  0 + l15];
        float v1 = sacc[mt][1][r]*scale + bt[q*64 + 16 + l15];
        float v2 = sacc[mt][2][r]*scale + bt[q*64 + 32 + l15];
        float v3 = sacc[mt][3][r]*scale + bt[q*64 + 48 + l15];
        float m = fmaxf(fmaxf(v0,v1), fmaxf(v2,v3));
        #pragma unroll
        for (int off=1; off<16; off<<=1) m = fmaxf(m, __shfl_xor(m, off));
        v0 = __expf(v0-m); v1 = __expf(v1-m); v2 = __expf(v2-m); v3 = __expf(v3-m);
        float s = v0+v1+v2+v3;
        #pragma unroll
        for (int off=1; off<16; off<<=1) s += __shfl_xor(s, off);
        rs[mt][r] = s;
        Pw[q*PSTR +  0 + l15] = (__bf16)v0;
        Pw[q*PSTR + 16 + l15] = (__bf16)v1;
        Pw[q*PSTR + 32 + l15] = (__bf16)v2;
        Pw[q*PSTR + 48 + l15] = (__bf16)v3;
      }
    }

    #pragma unroll
    for (int mt=0; mt<4; mt++) {
      #pragma unroll
      for (int dt=0; dt<2; dt++) {
        f32x4 o = (f32x4){0.f,0.f,0.f,0.f};
        #pragma unroll
        for (int ks=0; ks<2; ks++) {
          bf16x8 pa = *(const bf16x8*)(Pw  + (16*mt + l15)*PSTR + 32*ks + 8*g);
          bf16x8 vb = *(const bf16x8*)(VTw + (16*dt + l15)*PSTR + 32*ks + 8*g);
          o = mfma16(pa, vb, o);
        }
        #pragma unroll
        for (int r=0; r<4; r++) {
          int q = 16*mt + 4*g + r;
          if (q < NTOK)
            qao[rowbase + (size_t)q*DIM + h*HD + 16*dt + l15] = (__bf16)(o[r] / rs[mt][r]);
        }
      }
    }
  }
}

// ---------------- output projection, all-bf16 LDS: out = AO @ proj_w^T + b ----
__global__ __launch_bounds__(256, 4) void k_proj(
    const __bf16* __restrict__ Aao, const __bf16* __restrict__ pw_bf,
    const float* __restrict__ pb, float* __restrict__ out)
{
  // 4704 = 8 * 588 : bijective XCD swizzle
  int b = blockIdx.x;
  int orig = (b & 7) * 588 + (b >> 3);
  int mtile = orig / 3;
  int nt = orig - mtile*3;
  int lane = threadIdx.x & 63, wave = threadIdx.x >> 6;
  int l15 = lane & 15, g = lane >> 4;
  int wr = (wave >> 1) * 64, wc = (wave & 1) * 64;
  int row0b = mtile*128;
  int col00 = nt*128;

  __shared__ __align__(16) __bf16 As[2][128*32];
  __shared__ __align__(16) __bf16 Bs[2][128*32];

  int sr  = 2*(lane >> 3) + ((lane >> 2) & 1);
  int scb = (lane & 3) ^ ((lane >> 3) & 3);
  const __bf16* asrc[2]; const __bf16* bsrc[2];
  #pragma unroll
  for (int j = 0; j < 2; ++j) {
    int ar = (wave*2 + j)*16 + sr;
    asrc[j] = Aao   + (size_t)(row0b + ar)*DIM + scb*8;
    bsrc[j] = pw_bf + (size_t)(col00 + ar)*DIM + scb*8;
  }

  f32x4 acc[4][4];
  #pragma unroll
  for (int a=0;a<4;a++)
    #pragma unroll
    for (int bb=0;bb<4;bb++) acc[a][bb] = (f32x4){0.f,0.f,0.f,0.f};

  #pragma unroll
  for (int j = 0; j < 2; ++j) {
    gload_lds16(asrc[j], (char*)&As[0][0] + (wave*2+j)*1024);
    gload_lds16(bsrc[j], (char*)&Bs[0][0] + (wave*2+j)*1024);
  }
  __syncthreads();

  int lslot = l15*64 + ((g ^ ((l15 >> 1) & 3)) << 4);

  int buf = 0;
  #pragma unroll 2
  for (int kt = 0; kt < 12; ++kt) {
    if (kt < 11) {
      int kk = (kt+1)*32;
      #pragma unroll
      for (int j = 0; j < 2; ++j) {
        gload_lds16(asrc[j] + kk, (char*)&As[buf^1][0] + (wave*2+j)*1024);
        gload_lds16(bsrc[j] + kk, (char*)&Bs[buf^1][0] + (wave*2+j)*1024);
      }
    }
    bf16x8 af[4], bfv[4];
    #pragma unroll
    for (int a=0;a<4;a++)
      af[a]  = *(const bf16x8*)((const char*)&As[buf][0] + (wr + a*16)*64 + lslot);
    #pragma unroll
    for (int bb=0;bb<4;bb++)
      bfv[bb] = *(const bf16x8*)((const char*)&Bs[buf][0] + (wc + bb*16)*64 + lslot);
    #pragma unroll
    for (int a=0;a<4;a++)
      #pragma unroll
      for (int bb=0;bb<4;bb++)
        acc[a][bb] = mfma16(af[a], bfv[bb], acc[a][bb]);
    __syncthreads();
    buf ^= 1;
  }

  #pragma unroll
  for (int a=0;a<4;a++) {
    #pragma unroll
    for (int bb=0;bb<4;bb++) {
      int col = col00 + wc + bb*16 + l15;
      float bi = pb[col];
      size_t cbase = (size_t)(row0b + wr + a*16 + 4*g)*DIM + col;
      #pragma unroll
      for (int r=0;r<4;r++)
        out[cbase + (size_t)r*DIM] = acc[a][bb][r] + bi;
    }
  }
}

extern "C" void kernel_launch(void* const* d_in, const int* in_sizes, int n_in,
                              void* d_out, int out_size, void* d_ws, size_t ws_size,
                              hipStream_t stream)
{
  const float* x   = (const float*)d_in[0];
  const float* y   = (const float*)d_in[1];
  const float* qw  = (const float*)d_in[2];
  const float* qb  = (const float*)d_in[3];
  const float* kvw = (const float*)d_in[4];
  const float* kvb = (const float*)d_in[5];
  const float* pw  = (const float*)d_in[6];
  const float* pb  = (const float*)d_in[7];
  const float* rt  = (const float*)d_in[8];
  const int*   ri  = (const int*)d_in[9];
  float* out = (float*)d_out;

  char* ws = (char*)d_ws;
  const size_t WS_NEEDED = 1376256ull + 3ull*154140672ull;
  if (ws_size < WS_NEEDED) return;

  __bf16* qw_bf    = (__bf16*)(ws);
  __bf16* kvw_bf   = (__bf16*)(ws + 294912);
  __bf16* pw_bf    = (__bf16*)(ws + 884736);
  float*  bias_pad = (float*)(ws + 1179648);
  __bf16* Qws      = (__bf16*)(ws + 1376256);
  __bf16* Kws      = Qws + (size_t)MTOT*DIM;
  __bf16* Vws      = Kws + (size_t)MTOT*DIM;

  k_prep<<<dim3(1152), dim3(256), 0, stream>>>(qw, kvw, pw, rt, ri, qw_bf, kvw_bf, pw_bf, bias_pad);
  k_qkv <<<dim3(1568*9), dim3(256), 0, stream>>>(x, y, qw_bf, kvw_bf, qb, kvb, Qws, Kws, Vws);
  k_attn<<<dim3(NWIN), dim3(256), 0, stream>>>(Qws, Kws, Vws, bias_pad);
  k_proj<<<dim3(1568*3), dim3(256), 0, stream>>>(Qws, pw_bf, pb, out);
}

// Round 5
// 846.044 us; speedup vs baseline: 1.1239x; 1.0208x over previous
//
#include <hip/hip_runtime.h>

#define DIM 384
#define HEADS 12
#define HD 32
#define NTOK 49
#define NWIN 4096
#define MTOT (NWIN*NTOK)   // 200704 = 1568 * 128
#define PSTR 72            // padded LDS row stride (elements) for P and V^T

typedef __attribute__((ext_vector_type(8))) __bf16 bf16x8;
typedef __attribute__((ext_vector_type(4))) __bf16 bf16x4;
typedef __attribute__((ext_vector_type(4))) float f32x4;

static __device__ __forceinline__ f32x4 mfma16(bf16x8 a, bf16x8 b, f32x4 c) {
  return __builtin_amdgcn_mfma_f32_16x16x32_bf16(a, b, c, 0, 0, 0);
}

// async global->LDS, 16B per lane: dest = lds_base(wave-uniform) + lane*16
static __device__ __forceinline__ void gload_lds16(const void* g, void* l) {
  __builtin_amdgcn_global_load_lds(
      (const __attribute__((address_space(1))) unsigned int*)g,
      (__attribute__((address_space(3))) unsigned int*)l, 16, 0, 0);
}

static __device__ __forceinline__ bf16x4 cvt4(float4 v) {
  bf16x4 t;
  t[0]=(__bf16)v.x; t[1]=(__bf16)v.y; t[2]=(__bf16)v.z; t[3]=(__bf16)v.w;
  return t;
}

// ---------------- prep: weights -> bf16, bias table expand ----------------
__global__ void k_prep(const float* __restrict__ qw, const float* __restrict__ kvw,
                       const float* __restrict__ pw, const float* __restrict__ rel_table,
                       const int* __restrict__ rel_index,
                       __bf16* __restrict__ qw_bf, __bf16* __restrict__ kvw_bf,
                       __bf16* __restrict__ pw_bf, float* __restrict__ bias_pad) {
  int i = blockIdx.x * 256 + threadIdx.x;
  if (i < DIM*DIM)   qw_bf[i] = (__bf16)qw[i];
  if (i < 2*DIM*DIM) kvw_bf[i] = (__bf16)kvw[i];
  if (i < DIM*DIM)   pw_bf[i] = (__bf16)pw[i];
  if (i < HEADS*64*64) {
    int h = i >> 12, rem = i & 4095, q = rem >> 6, k = rem & 63;
    float v;
    if (k >= NTOK)      v = -1e30f;   // key padding: masks softmax for free
    else if (q >= NTOK) v = 0.0f;     // query padding rows are discarded
    else v = rel_table[rel_index[q*NTOK + k] * HEADS + h];
    bias_pad[i] = v;
  }
}

// ---------------- fused QKV GEMM: f32 A reg-staged -> bf16 LDS (swizzled) ----
// A staging, COALESCED: load instr j covers rows wave*32+j*8+(lane>>3),
// 16B chunk lane&7 -> 8 consecutive lanes read 128B contiguous (16 lines/instr,
// was 64). Each lane commits its 4 chunks as 4x ds_write_b64 into the same
// paired-row 2-bit-XOR swizzled layout the reads use (write covers 8 full 64B
// rows per instr -> all 32 banks even -> conflict-free).
__global__ __launch_bounds__(256, 4) void k_qkv(
    const float* __restrict__ x, const float* __restrict__ y,
    const __bf16* __restrict__ qw_bf, const __bf16* __restrict__ kvw_bf,
    const float* __restrict__ q_b, const float* __restrict__ kv_b,
    __bf16* __restrict__ Qws, __bf16* __restrict__ Kws, __bf16* __restrict__ Vws)
{
  // 14112 = 8 * 1764 : bijective XCD swizzle; 9 col-tiles of one mtile stay on one XCD
  int b = blockIdx.x;
  int orig = (b & 7) * 1764 + (b >> 3);
  int mtile = orig / 9;
  int nt9 = orig - mtile*9;
  const float* A; const __bf16* Bw; const float* bias; __bf16* Cout;
  int wrow0, col0;
  if (nt9 < 3) { A = x; Bw = qw_bf; bias = q_b; Cout = Qws; wrow0 = nt9*128; col0 = wrow0; }
  else {
    A = y; Bw = kvw_bf; bias = kv_b; wrow0 = (nt9-3)*128;
    if (wrow0 < DIM) { Cout = Kws; col0 = wrow0; } else { Cout = Vws; col0 = wrow0 - DIM; }
  }
  bias += wrow0;

  __shared__ __align__(16) __bf16 As[2][128*32];   // 8 KB each
  __shared__ __align__(16) __bf16 Bs[2][128*32];   // 8 KB each

  int t = threadIdx.x, lane = t & 63, wave = t >> 6;
  int l15 = lane & 15, g = lane >> 4;
  int wr = (wave >> 1) * 64, wc = (wave & 1) * 64;
  int row0b = mtile*128;

  // ---- A staging geometry (coalesced reg path) ----
  int c8 = lane & 7;            // 16B chunk within the 128B f32 row
  int r8 = lane >> 3;           // row within the 8-row instruction group
  int swk = (lane >> 4) & 3;    // == ((row)>>1)&3 for every j (j*8, wave*32 even)
  // global: row (row0b + wave*32 + j*8 + r8), f32 col c8*4; +kk per K-step
  const float* asrc = A + (size_t)(row0b + wave*32 + r8)*DIM + c8*4;
  // LDS: row*64B + swizzled slot; +j*512 per instr, wave*2048 base
  unsigned lwb = (unsigned)wave*2048 + (unsigned)r8*64
               + ((((c8 >> 1) ^ swk) << 4) + (c8 & 1)*8);

  // ---- B staging geometry (global_load_lds, pre-swizzled source) ----
  int sr  = 2*(lane >> 3) + ((lane >> 2) & 1);
  int scb = (lane & 3) ^ ((lane >> 3) & 3);
  const __bf16* bsrc[2];
  #pragma unroll
  for (int j = 0; j < 2; ++j)
    bsrc[j] = Bw + (size_t)(wrow0 + (wave*2 + j)*16 + sr)*DIM + scb*8;

  f32x4 acc[4][4];
  #pragma unroll
  for (int a=0;a<4;a++)
    #pragma unroll
    for (int bb=0;bb<4;bb++) acc[a][bb] = (f32x4){0.f,0.f,0.f,0.f};

  float4 r0, r1, r2, r3;
  // prologue: stage K-step 0
  r0 = *(const float4*)(asrc);
  r1 = *(const float4*)(asrc +  8*DIM);
  r2 = *(const float4*)(asrc + 16*DIM);
  r3 = *(const float4*)(asrc + 24*DIM);
  #pragma unroll
  for (int j = 0; j < 2; ++j)
    gload_lds16(bsrc[j], (char*)&Bs[0][0] + (wave*2+j)*1024);
  *(bf16x4*)((char*)&As[0][0] + lwb +    0) = cvt4(r0);
  *(bf16x4*)((char*)&As[0][0] + lwb +  512) = cvt4(r1);
  *(bf16x4*)((char*)&As[0][0] + lwb + 1024) = cvt4(r2);
  *(bf16x4*)((char*)&As[0][0] + lwb + 1536) = cvt4(r3);
  __syncthreads();

  // ds_read address: logical row r at byte r*64 + 16*(g ^ ((r>>1)&3)); with
  // r = base16 + l15 and base16 % 16 == 0, (r>>1)&3 == (l15>>1)&3 — lane-const.
  int lslot = l15*64 + ((g ^ ((l15 >> 1) & 3)) << 4);

  int buf = 0;
  #pragma unroll 2
  for (int kt = 0; kt < 12; ++kt) {
    if (kt < 11) {
      int kk = (kt+1)*32;
      // issue next-tile loads EARLY (latency hides under this tile's MFMA)
      r0 = *(const float4*)(asrc + kk);
      r1 = *(const float4*)(asrc + kk +  8*DIM);
      r2 = *(const float4*)(asrc + kk + 16*DIM);
      r3 = *(const float4*)(asrc + kk + 24*DIM);
      #pragma unroll
      for (int j = 0; j < 2; ++j)
        gload_lds16(bsrc[j] + kk, (char*)&Bs[buf^1][0] + (wave*2+j)*1024);
    }
    bf16x8 af[4], bfv[4];
    #pragma unroll
    for (int a=0;a<4;a++)
      af[a]  = *(const bf16x8*)((const char*)&As[buf][0] + (wr + a*16)*64 + lslot);
    #pragma unroll
    for (int bb=0;bb<4;bb++)
      bfv[bb] = *(const bf16x8*)((const char*)&Bs[buf][0] + (wc + bb*16)*64 + lslot);
    #pragma unroll
    for (int a=0;a<4;a++)
      #pragma unroll
      for (int bb=0;bb<4;bb++)
        acc[a][bb] = mfma16(af[a], bfv[bb], acc[a][bb]);
    if (kt < 11) {
      // write-late: convert and commit next tile after MFMAs issued
      *(bf16x4*)((char*)&As[buf^1][0] + lwb +    0) = cvt4(r0);
      *(bf16x4*)((char*)&As[buf^1][0] + lwb +  512) = cvt4(r1);
      *(bf16x4*)((char*)&As[buf^1][0] + lwb + 1024) = cvt4(r2);
      *(bf16x4*)((char*)&As[buf^1][0] + lwb + 1536) = cvt4(r3);
    }
    __syncthreads();
    buf ^= 1;
  }

  #pragma unroll
  for (int a=0;a<4;a++) {
    #pragma unroll
    for (int bb=0;bb<4;bb++) {
      int colw = wc + bb*16 + l15;
      float bi = bias[colw];
      size_t cbase = (size_t)(row0b + wr + a*16 + 4*g)*DIM + (col0 + colw);
      #pragma unroll
      for (int r=0;r<4;r++)
        Cout[cbase + (size_t)r*DIM] = (__bf16)(acc[a][bb][r] + bi);
    }
  }
}

// ---------------- per-window attention (12 heads), writes attn_out over Q ----------------
__global__ __launch_bounds__(256) void k_attn(
    __bf16* qao,   // Q in, attn_out out (ALIASED — intentionally not restrict)
    const __bf16* __restrict__ Kws, const __bf16* __restrict__ Vws,
    const float* __restrict__ bias_pad)
{
  __shared__ __align__(16) __bf16 Psh[4][64*PSTR];
  __shared__ __align__(16) __bf16 VTsh[4][32*PSTR];
  int b = blockIdx.x;
  int lane = threadIdx.x & 63, wave = threadIdx.x >> 6;
  int l15 = lane & 15, g = lane >> 4;
  __bf16* Pw  = Psh[wave];
  __bf16* VTw = VTsh[wave];
  size_t rowbase = (size_t)b * NTOK * DIM;
  const float scale = 0.17677669529663687f;  // 32^-0.5

  for (int e = lane; e < 32*15; e += 64) {
    int d = e / 15, k = 49 + (e - d*15);
    VTw[d*PSTR + k] = (__bf16)0.0f;
  }

  for (int hh = 0; hh < 3; hh++) {
    int h = wave + hh*4;
    for (int e = lane; e < NTOK*HD; e += 64) {
      int k = e >> 5, d = e & 31;
      VTw[d*PSTR + k] = Vws[rowbase + (size_t)k*DIM + h*HD + d];
    }
    bf16x8 qf[4], kf[4];
    #pragma unroll
    for (int mt=0; mt<4; mt++) {
      int q = 16*mt + l15; if (q > 48) q = 48;
      qf[mt] = *(const bf16x8*)(qao + rowbase + (size_t)q*DIM + h*HD + g*8);
    }
    #pragma unroll
    for (int nt=0; nt<4; nt++) {
      int kk = 16*nt + l15; if (kk > 48) kk = 48;
      kf[nt] = *(const bf16x8*)(Kws + rowbase + (size_t)kk*DIM + h*HD + g*8);
    }
    f32x4 sacc[4][4];
    #pragma unroll
    for (int mt=0; mt<4; mt++)
      #pragma unroll
      for (int nt=0; nt<4; nt++)
        sacc[mt][nt] = mfma16(qf[mt], kf[nt], (f32x4){0.f,0.f,0.f,0.f});

    const float* bt = bias_pad + h*4096;
    float rs[4][4];
    #pragma unroll
    for (int mt=0; mt<4; mt++) {
      #pragma unroll
      for (int r=0; r<4; r++) {
        int q = 16*mt + 4*g + r;
        float v0 = sacc[mt][0][r]*scale + bt[q*64 +  0 + l15];
        float v1 = sacc[mt][1][r]*scale + bt[q*64 + 16 + l15];
        float v2 = sacc[mt][2][r]*scale + bt[q*64 + 32 + l15];
        float v3 = sacc[mt][3][r]*scale + bt[q*64 + 48 + l15];
        float m = fmaxf(fmaxf(v0,v1), fmaxf(v2,v3));
        #pragma unroll
        for (int off=1; off<16; off<<=1) m = fmaxf(m, __shfl_xor(m, off));
        v0 = __expf(v0-m); v1 = __expf(v1-m); v2 = __expf(v2-m); v3 = __expf(v3-m);
        float s = v0+v1+v2+v3;
        #pragma unroll
        for (int off=1; off<16; off<<=1) s += __shfl_xor(s, off);
        rs[mt][r] = s;
        Pw[q*PSTR +  0 + l15] = (__bf16)v0;
        Pw[q*PSTR + 16 + l15] = (__bf16)v1;
        Pw[q*PSTR + 32 + l15] = (__bf16)v2;
        Pw[q*PSTR + 48 + l15] = (__bf16)v3;
      }
    }

    #pragma unroll
    for (int mt=0; mt<4; mt++) {
      #pragma unroll
      for (int dt=0; dt<2; dt++) {
        f32x4 o = (f32x4){0.f,0.f,0.f,0.f};
        #pragma unroll
        for (int ks=0; ks<2; ks++) {
          bf16x8 pa = *(const bf16x8*)(Pw  + (16*mt + l15)*PSTR + 32*ks + 8*g);
          bf16x8 vb = *(const bf16x8*)(VTw + (16*dt + l15)*PSTR + 32*ks + 8*g);
          o = mfma16(pa, vb, o);
        }
        #pragma unroll
        for (int r=0; r<4; r++) {
          int q = 16*mt + 4*g + r;
          if (q < NTOK)
            qao[rowbase + (size_t)q*DIM + h*HD + 16*dt + l15] = (__bf16)(o[r] / rs[mt][r]);
        }
      }
    }
  }
}

// ---------------- output projection, all-bf16 LDS: out = AO @ proj_w^T + b ----
__global__ __launch_bounds__(256, 4) void k_proj(
    const __bf16* __restrict__ Aao, const __bf16* __restrict__ pw_bf,
    const float* __restrict__ pb, float* __restrict__ out)
{
  // 4704 = 8 * 588 : bijective XCD swizzle
  int b = blockIdx.x;
  int orig = (b & 7) * 588 + (b >> 3);
  int mtile = orig / 3;
  int nt = orig - mtile*3;
  int lane = threadIdx.x & 63, wave = threadIdx.x >> 6;
  int l15 = lane & 15, g = lane >> 4;
  int wr = (wave >> 1) * 64, wc = (wave & 1) * 64;
  int row0b = mtile*128;
  int col00 = nt*128;

  __shared__ __align__(16) __bf16 As[2][128*32];
  __shared__ __align__(16) __bf16 Bs[2][128*32];

  int sr  = 2*(lane >> 3) + ((lane >> 2) & 1);
  int scb = (lane & 3) ^ ((lane >> 3) & 3);
  const __bf16* asrc[2]; const __bf16* bsrc[2];
  #pragma unroll
  for (int j = 0; j < 2; ++j) {
    int ar = (wave*2 + j)*16 + sr;
    asrc[j] = Aao   + (size_t)(row0b + ar)*DIM + scb*8;
    bsrc[j] = pw_bf + (size_t)(col00 + ar)*DIM + scb*8;
  }

  f32x4 acc[4][4];
  #pragma unroll
  for (int a=0;a<4;a++)
    #pragma unroll
    for (int bb=0;bb<4;bb++) acc[a][bb] = (f32x4){0.f,0.f,0.f,0.f};

  #pragma unroll
  for (int j = 0; j < 2; ++j) {
    gload_lds16(asrc[j], (char*)&As[0][0] + (wave*2+j)*1024);
    gload_lds16(bsrc[j], (char*)&Bs[0][0] + (wave*2+j)*1024);
  }
  __syncthreads();

  int lslot = l15*64 + ((g ^ ((l15 >> 1) & 3)) << 4);

  int buf = 0;
  #pragma unroll 2
  for (int kt = 0; kt < 12; ++kt) {
    if (kt < 11) {
      int kk = (kt+1)*32;
      #pragma unroll
      for (int j = 0; j < 2; ++j) {
        gload_lds16(asrc[j] + kk, (char*)&As[buf^1][0] + (wave*2+j)*1024);
        gload_lds16(bsrc[j] + kk, (char*)&Bs[buf^1][0] + (wave*2+j)*1024);
      }
    }
    bf16x8 af[4], bfv[4];
    #pragma unroll
    for (int a=0;a<4;a++)
      af[a]  = *(const bf16x8*)((const char*)&As[buf][0] + (wr + a*16)*64 + lslot);
    #pragma unroll
    for (int bb=0;bb<4;bb++)
      bfv[bb] = *(const bf16x8*)((const char*)&Bs[buf][0] + (wc + bb*16)*64 + lslot);
    #pragma unroll
    for (int a=0;a<4;a++)
      #pragma unroll
      for (int bb=0;bb<4;bb++)
        acc[a][bb] = mfma16(af[a], bfv[bb], acc[a][bb]);
    __syncthreads();
    buf ^= 1;
  }

  #pragma unroll
  for (int a=0;a<4;a++) {
    #pragma unroll
    for (int bb=0;bb<4;bb++) {
      int col = col00 + wc + bb*16 + l15;
      float bi = pb[col];
      size_t cbase = (size_t)(row0b + wr + a*16 + 4*g)*DIM + col;
      #pragma unroll
      for (int r=0;r<4;r++)
        out[cbase + (size_t)r*DIM] = acc[a][bb][r] + bi;
    }
  }
}

extern "C" void kernel_launch(void* const* d_in, const int* in_sizes, int n_in,
                              void* d_out, int out_size, void* d_ws, size_t ws_size,
                              hipStream_t stream)
{
  const float* x   = (const float*)d_in[0];
  const float* y   = (const float*)d_in[1];
  const float* qw  = (const float*)d_in[2];
  const float* qb  = (const float*)d_in[3];
  const float* kvw = (const float*)d_in[4];
  const float* kvb = (const float*)d_in[5];
  const float* pw  = (const float*)d_in[6];
  const float* pb  = (const float*)d_in[7];
  const float* rt  = (const float*)d_in[8];
  const int*   ri  = (const int*)d_in[9];
  float* out = (float*)d_out;

  char* ws = (char*)d_ws;
  const size_t WS_NEEDED = 1376256ull + 3ull*154140672ull;
  if (ws_size < WS_NEEDED) return;

  __bf16* qw_bf    = (__bf16*)(ws);
  __bf16* kvw_bf   = (__bf16*)(ws + 294912);
  __bf16* pw_bf    = (__bf16*)(ws + 884736);
  float*  bias_pad = (float*)(ws + 1179648);
  __bf16* Qws      = (__bf16*)(ws + 1376256);
  __bf16* Kws      = Qws + (size_t)MTOT*DIM;
  __bf16* Vws      = Kws + (size_t)MTOT*DIM;

  k_prep<<<dim3(1152), dim3(256), 0, stream>>>(qw, kvw, pw, rt, ri, qw_bf, kvw_bf, pw_bf, bias_pad);
  k_qkv <<<dim3(1568*9), dim3(256), 0, stream>>>(x, y, qw_bf, kvw_bf, qb, kvb, Qws, Kws, Vws);
  k_attn<<<dim3(NWIN), dim3(256), 0, stream>>>(Qws, Kws, Vws, bias_pad);
  k_proj<<<dim3(1568*3), dim3(256), 0, stream>>>(Qws, pw_bf, pb, out);
}

// Round 6
// 840.815 us; speedup vs baseline: 1.1309x; 1.0062x over previous
//
#include <hip/hip_runtime.h>

#define DIM 384
#define HEADS 12
#define HD 32
#define NTOK 49
#define NWIN 4096
#define MTOT (NWIN*NTOK)   // 200704 = 1568 * 128
#define PSTR 72            // padded LDS row stride (elements) for P and V^T

typedef __attribute__((ext_vector_type(8))) __bf16 bf16x8;
typedef __attribute__((ext_vector_type(4))) __bf16 bf16x4;
typedef __attribute__((ext_vector_type(4))) float f32x4;

static __device__ __forceinline__ f32x4 mfma16(bf16x8 a, bf16x8 b, f32x4 c) {
  return __builtin_amdgcn_mfma_f32_16x16x32_bf16(a, b, c, 0, 0, 0);
}

// async global->LDS, 16B per lane: dest = lds_base(wave-uniform) + lane*16
static __device__ __forceinline__ void gload_lds16(const void* g, void* l) {
  __builtin_amdgcn_global_load_lds(
      (const __attribute__((address_space(1))) unsigned int*)g,
      (__attribute__((address_space(3))) unsigned int*)l, 16, 0, 0);
}

static __device__ __forceinline__ bf16x4 cvt4(float4 v) {
  bf16x4 t;
  t[0]=(__bf16)v.x; t[1]=(__bf16)v.y; t[2]=(__bf16)v.z; t[3]=(__bf16)v.w;
  return t;
}

// ---------------- prep: weights -> bf16, bias table expand ----------------
__global__ void k_prep(const float* __restrict__ qw, const float* __restrict__ kvw,
                       const float* __restrict__ pw, const float* __restrict__ rel_table,
                       const int* __restrict__ rel_index,
                       __bf16* __restrict__ qw_bf, __bf16* __restrict__ kvw_bf,
                       __bf16* __restrict__ pw_bf, float* __restrict__ bias_pad) {
  int i = blockIdx.x * 256 + threadIdx.x;
  if (i < DIM*DIM)   qw_bf[i] = (__bf16)qw[i];
  if (i < 2*DIM*DIM) kvw_bf[i] = (__bf16)kvw[i];
  if (i < DIM*DIM)   pw_bf[i] = (__bf16)pw[i];
  if (i < HEADS*64*64) {
    int h = i >> 12, rem = i & 4095, q = rem >> 6, k = rem & 63;
    float v;
    if (k >= NTOK)      v = -1e30f;   // key padding: masks softmax for free
    else if (q >= NTOK) v = 0.0f;     // query padding rows are discarded
    else v = rel_table[rel_index[q*NTOK + k] * HEADS + h];
    bias_pad[i] = v;
  }
}

// ---------------- fused QKV GEMM: counted-vmcnt pipeline ----------------
// A (f32): reg-staged 1 step ahead (coalesced 128B-per-8-lanes), cvt->ds_write
// into 2-buffer swizzled LDS. B (bf16 weights): global_load_lds issued 2 steps
// ahead into a 3-buffer ring. Raw s_barrier + counted s_waitcnt — B loads stay
// in flight ACROSS barriers; no vmcnt(0) drain until the tail (T3/T4).
__global__ __launch_bounds__(256, 4) void k_qkv(
    const float* __restrict__ x, const float* __restrict__ y,
    const __bf16* __restrict__ qw_bf, const __bf16* __restrict__ kvw_bf,
    const float* __restrict__ q_b, const float* __restrict__ kv_b,
    __bf16* __restrict__ Qws, __bf16* __restrict__ Kws, __bf16* __restrict__ Vws)
{
  // 14112 = 8 * 1764 : bijective XCD swizzle; 9 col-tiles of one mtile stay on one XCD
  int b = blockIdx.x;
  int orig = (b & 7) * 1764 + (b >> 3);
  int mtile = orig / 9;
  int nt9 = orig - mtile*9;
  const float* A; const __bf16* Bw; const float* bias; __bf16* Cout;
  int wrow0, col0;
  if (nt9 < 3) { A = x; Bw = qw_bf; bias = q_b; Cout = Qws; wrow0 = nt9*128; col0 = wrow0; }
  else {
    A = y; Bw = kvw_bf; bias = kv_b; wrow0 = (nt9-3)*128;
    if (wrow0 < DIM) { Cout = Kws; col0 = wrow0; } else { Cout = Vws; col0 = wrow0 - DIM; }
  }
  bias += wrow0;

  __shared__ __align__(16) __bf16 As[2*128*32];   // 2 x 8 KB (double buffer)
  __shared__ __align__(16) __bf16 Bs[3*128*32];   // 3 x 8 KB (ring, 2-deep prefetch)

  int t = threadIdx.x, lane = t & 63, wave = t >> 6;
  int l15 = lane & 15, g = lane >> 4;
  int wr = (wave >> 1) * 64, wc = (wave & 1) * 64;
  int row0b = mtile*128;

  // ---- A staging geometry (coalesced reg path) ----
  int c8 = lane & 7;            // 16B chunk within the 128B f32 row
  int r8 = lane >> 3;           // row within the 8-row instruction group
  int swk = (lane >> 4) & 3;    // == ((row)>>1)&3 for every chunk
  const float* asrc = A + (size_t)(row0b + wave*32 + r8)*DIM + c8*4;
  unsigned lwb = (unsigned)wave*2048 + (unsigned)r8*64
               + ((((c8 >> 1) ^ swk) << 4) + (c8 & 1)*8);

  // ---- B staging geometry (global_load_lds, pre-swizzled source) ----
  int sr  = 2*(lane >> 3) + ((lane >> 2) & 1);
  int scb = (lane & 3) ^ ((lane >> 3) & 3);
  const __bf16* bsrc0 = Bw + (size_t)(wrow0 + (wave*2    )*16 + sr)*DIM + scb*8;
  const __bf16* bsrc1 = Bw + (size_t)(wrow0 + (wave*2 + 1)*16 + sr)*DIM + scb*8;

  f32x4 acc[4][4];
  #pragma unroll
  for (int a=0;a<4;a++)
    #pragma unroll
    for (int bb=0;bb<4;bb++) acc[a][bb] = (f32x4){0.f,0.f,0.f,0.f};

  // ---- prologue: A(0) regs; B(0),B(1) gloads; commit A(0); counted wait ----
  {
    float4 s0 = *(const float4*)(asrc);
    float4 s1 = *(const float4*)(asrc +  8*DIM);
    float4 s2 = *(const float4*)(asrc + 16*DIM);
    float4 s3 = *(const float4*)(asrc + 24*DIM);
    gload_lds16(bsrc0,      (char*)Bs +        (wave*2  )*1024);
    gload_lds16(bsrc1,      (char*)Bs +        (wave*2+1)*1024);
    gload_lds16(bsrc0 + 32, (char*)Bs + 8192 + (wave*2  )*1024);
    gload_lds16(bsrc1 + 32, (char*)Bs + 8192 + (wave*2+1)*1024);
    // compiler inserts vmcnt(4) before these uses (A loads are the 4 oldest)
    *(bf16x4*)((char*)As + lwb +    0) = cvt4(s0);
    *(bf16x4*)((char*)As + lwb +  512) = cvt4(s1);
    *(bf16x4*)((char*)As + lwb + 1024) = cvt4(s2);
    *(bf16x4*)((char*)As + lwb + 1536) = cvt4(s3);
    asm volatile("s_waitcnt vmcnt(2)" ::: "memory");   // B(0) done; B(1) in flight
    asm volatile("s_waitcnt lgkmcnt(0)" ::: "memory"); // A(0) ds_writes visible
    __builtin_amdgcn_s_barrier();
  }

  // ds_read slot: logical row r at byte r*64 + 16*(g ^ ((r>>1)&3))
  int lslot = l15*64 + ((g ^ ((l15 >> 1) & 3)) << 4);

  #pragma unroll
  for (int kt = 0; kt < 12; ++kt) {
    const int cur2 = kt & 1, nxt2 = cur2 ^ 1;
    const int cur3 = kt % 3, pre3 = (kt + 2) % 3;
    float4 s0, s1, s2, s3;
    if (kt < 11) {             // A loads for kt+1, issued EARLY
      int kk = (kt + 1) * 32;
      s0 = *(const float4*)(asrc + kk);
      s1 = *(const float4*)(asrc + kk +  8*DIM);
      s2 = *(const float4*)(asrc + kk + 16*DIM);
      s3 = *(const float4*)(asrc + kk + 24*DIM);
    }
    if (kt < 10) {             // B gloads for kt+2 (2-deep ring)
      int kk = (kt + 2) * 32;
      gload_lds16(bsrc0 + kk, (char*)Bs + pre3*8192 + (wave*2  )*1024);
      gload_lds16(bsrc1 + kk, (char*)Bs + pre3*8192 + (wave*2+1)*1024);
    }
    bf16x8 af[4], bfv[4];
    #pragma unroll
    for (int a=0;a<4;a++)
      af[a]  = *(const bf16x8*)((const char*)As + cur2*8192 + (wr + a*16)*64 + lslot);
    #pragma unroll
    for (int bb=0;bb<4;bb++)
      bfv[bb] = *(const bf16x8*)((const char*)Bs + cur3*8192 + (wc + bb*16)*64 + lslot);
    #pragma unroll
    for (int a=0;a<4;a++)
      #pragma unroll
      for (int bb=0;bb<4;bb++)
        acc[a][bb] = mfma16(af[a], bfv[bb], acc[a][bb]);
    if (kt < 11) {
      // write-late: compiler's wait for s0..s3 lands at vmcnt(2) — only the
      // A(kt+1) batch drains; B(kt+2) stays in flight across the barrier.
      *(bf16x4*)((char*)As + nxt2*8192 + lwb +    0) = cvt4(s0);
      *(bf16x4*)((char*)As + nxt2*8192 + lwb +  512) = cvt4(s1);
      *(bf16x4*)((char*)As + nxt2*8192 + lwb + 1024) = cvt4(s2);
      *(bf16x4*)((char*)As + nxt2*8192 + lwb + 1536) = cvt4(s3);
      if (kt < 10) asm volatile("s_waitcnt vmcnt(2)" ::: "memory");
      else         asm volatile("s_waitcnt vmcnt(0)" ::: "memory");
      asm volatile("s_waitcnt lgkmcnt(0)" ::: "memory");
      __builtin_amdgcn_s_barrier();
    }
  }

  #pragma unroll
  for (int a=0;a<4;a++) {
    #pragma unroll
    for (int bb=0;bb<4;bb++) {
      int colw = wc + bb*16 + l15;
      float bi = bias[colw];
      size_t cbase = (size_t)(row0b + wr + a*16 + 4*g)*DIM + (col0 + colw);
      #pragma unroll
      for (int r=0;r<4;r++)
        Cout[cbase + (size_t)r*DIM] = (__bf16)(acc[a][bb][r] + bi);
    }
  }
}

// ---------------- per-window attention (12 heads), writes attn_out over Q ----------------
__global__ __launch_bounds__(256) void k_attn(
    __bf16* qao,   // Q in, attn_out out (ALIASED — intentionally not restrict)
    const __bf16* __restrict__ Kws, const __bf16* __restrict__ Vws,
    const float* __restrict__ bias_pad)
{
  __shared__ __align__(16) __bf16 Psh[4][64*PSTR];
  __shared__ __align__(16) __bf16 VTsh[4][32*PSTR];
  int b = blockIdx.x;
  int lane = threadIdx.x & 63, wave = threadIdx.x >> 6;
  int l15 = lane & 15, g = lane >> 4;
  __bf16* Pw  = Psh[wave];
  __bf16* VTw = VTsh[wave];
  size_t rowbase = (size_t)b * NTOK * DIM;
  const float scale = 0.17677669529663687f;  // 32^-0.5

  for (int e = lane; e < 32*15; e += 64) {
    int d = e / 15, k = 49 + (e - d*15);
    VTw[d*PSTR + k] = (__bf16)0.0f;
  }

  for (int hh = 0; hh < 3; hh++) {
    int h = wave + hh*4;
    for (int e = lane; e < NTOK*HD; e += 64) {
      int k = e >> 5, d = e & 31;
      VTw[d*PSTR + k] = Vws[rowbase + (size_t)k*DIM + h*HD + d];
    }
    bf16x8 qf[4], kf[4];
    #pragma unroll
    for (int mt=0; mt<4; mt++) {
      int q = 16*mt + l15; if (q > 48) q = 48;
      qf[mt] = *(const bf16x8*)(qao + rowbase + (size_t)q*DIM + h*HD + g*8);
    }
    #pragma unroll
    for (int nt=0; nt<4; nt++) {
      int kk = 16*nt + l15; if (kk > 48) kk = 48;
      kf[nt] = *(const bf16x8*)(Kws + rowbase + (size_t)kk*DIM + h*HD + g*8);
    }
    f32x4 sacc[4][4];
    #pragma unroll
    for (int mt=0; mt<4; mt++)
      #pragma unroll
      for (int nt=0; nt<4; nt++)
        sacc[mt][nt] = mfma16(qf[mt], kf[nt], (f32x4){0.f,0.f,0.f,0.f});

    const float* bt = bias_pad + h*4096;
    float rs[4][4];
    #pragma unroll
    for (int mt=0; mt<4; mt++) {
      #pragma unroll
      for (int r=0; r<4; r++) {
        int q = 16*mt + 4*g + r;
        float v0 = sacc[mt][0][r]*scale + bt[q*64 +  0 + l15];
        float v1 = sacc[mt][1][r]*scale + bt[q*64 + 16 + l15];
        float v2 = sacc[mt][2][r]*scale + bt[q*64 + 32 + l15];
        float v3 = sacc[mt][3][r]*scale + bt[q*64 + 48 + l15];
        float m = fmaxf(fmaxf(v0,v1), fmaxf(v2,v3));
        #pragma unroll
        for (int off=1; off<16; off<<=1) m = fmaxf(m, __shfl_xor(m, off));
        v0 = __expf(v0-m); v1 = __expf(v1-m); v2 = __expf(v2-m); v3 = __expf(v3-m);
        float s = v0+v1+v2+v3;
        #pragma unroll
        for (int off=1; off<16; off<<=1) s += __shfl_xor(s, off);
        rs[mt][r] = s;
        Pw[q*PSTR +  0 + l15] = (__bf16)v0;
        Pw[q*PSTR + 16 + l15] = (__bf16)v1;
        Pw[q*PSTR + 32 + l15] = (__bf16)v2;
        Pw[q*PSTR + 48 + l15] = (__bf16)v3;
      }
    }

    #pragma unroll
    for (int mt=0; mt<4; mt++) {
      #pragma unroll
      for (int dt=0; dt<2; dt++) {
        f32x4 o = (f32x4){0.f,0.f,0.f,0.f};
        #pragma unroll
        for (int ks=0; ks<2; ks++) {
          bf16x8 pa = *(const bf16x8*)(Pw  + (16*mt + l15)*PSTR + 32*ks + 8*g);
          bf16x8 vb = *(const bf16x8*)(VTw + (16*dt + l15)*PSTR + 32*ks + 8*g);
          o = mfma16(pa, vb, o);
        }
        #pragma unroll
        for (int r=0; r<4; r++) {
          int q = 16*mt + 4*g + r;
          if (q < NTOK)
            qao[rowbase + (size_t)q*DIM + h*HD + 16*dt + l15] = (__bf16)(o[r] / rs[mt][r]);
        }
      }
    }
  }
}

// ---------------- output projection: counted-vmcnt pipeline, 3-buffer rings ----
__global__ __launch_bounds__(256, 4) void k_proj(
    const __bf16* __restrict__ Aao, const __bf16* __restrict__ pw_bf,
    const float* __restrict__ pb, float* __restrict__ out)
{
  // 4704 = 8 * 588 : bijective XCD swizzle
  int b = blockIdx.x;
  int orig = (b & 7) * 588 + (b >> 3);
  int mtile = orig / 3;
  int nt = orig - mtile*3;
  int lane = threadIdx.x & 63, wave = threadIdx.x >> 6;
  int l15 = lane & 15, g = lane >> 4;
  int wr = (wave >> 1) * 64, wc = (wave & 1) * 64;
  int row0b = mtile*128;
  int col00 = nt*128;

  __shared__ __align__(16) __bf16 As[3*128*32];   // 3 x 8 KB ring
  __shared__ __align__(16) __bf16 Bs[3*128*32];   // 3 x 8 KB ring

  int sr  = 2*(lane >> 3) + ((lane >> 2) & 1);
  int scb = (lane & 3) ^ ((lane >> 3) & 3);
  const __bf16* asrc0 = Aao   + (size_t)(row0b + (wave*2    )*16 + sr)*DIM + scb*8;
  const __bf16* asrc1 = Aao   + (size_t)(row0b + (wave*2 + 1)*16 + sr)*DIM + scb*8;
  const __bf16* bsrc0 = pw_bf + (size_t)(col00 + (wave*2    )*16 + sr)*DIM + scb*8;
  const __bf16* bsrc1 = pw_bf + (size_t)(col00 + (wave*2 + 1)*16 + sr)*DIM + scb*8;

  f32x4 acc[4][4];
  #pragma unroll
  for (int a=0;a<4;a++)
    #pragma unroll
    for (int bb=0;bb<4;bb++) acc[a][bb] = (f32x4){0.f,0.f,0.f,0.f};

  // prologue: stage batches 0 and 1; wait batch 0 only
  {
    gload_lds16(asrc0,      (char*)As +        (wave*2  )*1024);
    gload_lds16(asrc1,      (char*)As +        (wave*2+1)*1024);
    gload_lds16(bsrc0,      (char*)Bs +        (wave*2  )*1024);
    gload_lds16(bsrc1,      (char*)Bs +        (wave*2+1)*1024);
    gload_lds16(asrc0 + 32, (char*)As + 8192 + (wave*2  )*1024);
    gload_lds16(asrc1 + 32, (char*)As + 8192 + (wave*2+1)*1024);
    gload_lds16(bsrc0 + 32, (char*)Bs + 8192 + (wave*2  )*1024);
    gload_lds16(bsrc1 + 32, (char*)Bs + 8192 + (wave*2+1)*1024);
    asm volatile("s_waitcnt vmcnt(4)" ::: "memory");   // batch 0 done; batch 1 flying
    __builtin_amdgcn_s_barrier();
  }

  int lslot = l15*64 + ((g ^ ((l15 >> 1) & 3)) << 4);

  #pragma unroll
  for (int kt = 0; kt < 12; ++kt) {
    const int cur3 = kt % 3, pre3 = (kt + 2) % 3;
    if (kt < 10) {
      int kk = (kt + 2) * 32;
      gload_lds16(asrc0 + kk, (char*)As + pre3*8192 + (wave*2  )*1024);
      gload_lds16(asrc1 + kk, (char*)As + pre3*8192 + (wave*2+1)*1024);
      gload_lds16(bsrc0 + kk, (char*)Bs + pre3*8192 + (wave*2  )*1024);
      gload_lds16(bsrc1 + kk, (char*)Bs + pre3*8192 + (wave*2+1)*1024);
    }
    bf16x8 af[4], bfv[4];
    #pragma unroll
    for (int a=0;a<4;a++)
      af[a]  = *(const bf16x8*)((const char*)As + cur3*8192 + (wr + a*16)*64 + lslot);
    #pragma unroll
    for (int bb=0;bb<4;bb++)
      bfv[bb] = *(const bf16x8*)((const char*)Bs + cur3*8192 + (wc + bb*16)*64 + lslot);
    #pragma unroll
    for (int a=0;a<4;a++)
      #pragma unroll
      for (int bb=0;bb<4;bb++)
        acc[a][bb] = mfma16(af[a], bfv[bb], acc[a][bb]);
    if (kt < 11) {
      if (kt < 10) asm volatile("s_waitcnt vmcnt(4)" ::: "memory"); // batch kt+1 done, kt+2 flying
      else         asm volatile("s_waitcnt vmcnt(0)" ::: "memory"); // tail: batch 11 must land
      __builtin_amdgcn_s_barrier();
    }
  }

  #pragma unroll
  for (int a=0;a<4;a++) {
    #pragma unroll
    for (int bb=0;bb<4;bb++) {
      int col = col00 + wc + bb*16 + l15;
      float bi = pb[col];
      size_t cbase = (size_t)(row0b + wr + a*16 + 4*g)*DIM + col;
      #pragma unroll
      for (int r=0;r<4;r++)
        out[cbase + (size_t)r*DIM] = acc[a][bb][r] + bi;
    }
  }
}

extern "C" void kernel_launch(void* const* d_in, const int* in_sizes, int n_in,
                              void* d_out, int out_size, void* d_ws, size_t ws_size,
                              hipStream_t stream)
{
  const float* x   = (const float*)d_in[0];
  const float* y   = (const float*)d_in[1];
  const float* qw  = (const float*)d_in[2];
  const float* qb  = (const float*)d_in[3];
  const float* kvw = (const float*)d_in[4];
  const float* kvb = (const float*)d_in[5];
  const float* pw  = (const float*)d_in[6];
  const float* pb  = (const float*)d_in[7];
  const float* rt  = (const float*)d_in[8];
  const int*   ri  = (const int*)d_in[9];
  float* out = (float*)d_out;

  char* ws = (char*)d_ws;
  const size_t WS_NEEDED = 1376256ull + 3ull*154140672ull;
  if (ws_size < WS_NEEDED) return;

  __bf16* qw_bf    = (__bf16*)(ws);
  __bf16* kvw_bf   = (__bf16*)(ws + 294912);
  __bf16* pw_bf    = (__bf16*)(ws + 884736);
  float*  bias_pad = (float*)(ws + 1179648);
  __bf16* Qws      = (__bf16*)(ws + 1376256);
  __bf16* Kws      = Qws + (size_t)MTOT*DIM;
  __bf16* Vws      = Kws + (size_t)MTOT*DIM;

  k_prep<<<dim3(1152), dim3(256), 0, stream>>>(qw, kvw, pw, rt, ri, qw_bf, kvw_bf, pw_bf, bias_pad);
  k_qkv <<<dim3(1568*9), dim3(256), 0, stream>>>(x, y, qw_bf, kvw_bf, qb, kvb, Qws, Kws, Vws);
  k_attn<<<dim3(NWIN), dim3(256), 0, stream>>>(Qws, Kws, Vws, bias_pad);
  k_proj<<<dim3(1568*3), dim3(256), 0, stream>>>(Qws, pw_bf, pb, out);
}